// Round 2
// baseline (244.430 us; speedup 1.0000x reference)
//
#include <hip/hip_runtime.h>

typedef unsigned short u16;

#define CIN   64
#define HH    128
#define WW    128
#define NPIX  16384   /* HH*WW */
#define HID   256
#define MTOT  512     /* coef(256) + freq(256) stacked */
#define KTOT  576     /* 64 ch * 9 taps */
#define NB    4
#define WELEM 294912  /* MTOT*KTOT */

/* index-path constants: must bit-match the f32 trace of the reference */
#define SHM  ((float)(-0.0078125 + 1e-6))
#define SHP  ((float)( 0.0078125 + 1e-6))
#define CLO  ((float)(-1.0 + 1e-6))
#define CHI  ((float)( 1.0 - 1e-6))
#define PIF  3.14159265358979323846f

#define QSCL  1024.0f          /* int16 fixed-point scale */
#define QISCL (1.0f / 1024.0f)

using f32x4  = __attribute__((ext_vector_type(4))) float;
using bf16x8 = __attribute__((ext_vector_type(8))) short;

__device__ __forceinline__ u16 f2bf(float x) {
  union { float f; unsigned u; } v; v.f = x;
  unsigned r = v.u + 0x7FFFu + ((v.u >> 16) & 1u);
  return (u16)(r >> 16);
}
__device__ __forceinline__ float bf2f(u16 h) {
  union { unsigned u; float f; } v; v.u = ((unsigned)h) << 16;
  return v.f;
}

/* ---- storage-type helpers: fp32 (tier1) or int16 fixed-point (tier2) ---- */
__device__ __forceinline__ float ldv(const float* p) { return *p; }
__device__ __forceinline__ float ldv(const short* p) { return (float)(*p) * QISCL; }
__device__ __forceinline__ void ldpair(const float* p, float& a, float& b) {
  float2 v = *(const float2*)p; a = v.x; b = v.y;
}
__device__ __forceinline__ void ldpair(const short* p, float& a, float& b) {
  int u = *(const int*)p;
  a = (float)((short)(u & 0xFFFF)) * QISCL;
  b = (float)((short)(u >> 16)) * QISCL;
}
__device__ __forceinline__ void store4(float* p, float a, float b, float c, float d) {
  float4 v; v.x = a; v.y = b; v.z = c; v.w = d; *(float4*)p = v;
}
__device__ __forceinline__ unsigned packq(float a, float b) {
  float fa = fminf(fmaxf(a * QSCL, -32767.f), 32767.f);
  float fb = fminf(fmaxf(b * QSCL, -32767.f), 32767.f);
  int ia = (int)rintf(fa), ib = (int)rintf(fb);
  return ((unsigned)(unsigned short)(short)ia) | (((unsigned)(unsigned short)(short)ib) << 16);
}
__device__ __forceinline__ void store4(short* p, float a, float b, float c, float d) {
  uint2 v; v.x = packq(a, b); v.y = packq(c, d);
  *(uint2*)p = v;
}

/* =====================================================================
 * Kernel 1: repack conv weights -> split bf16 (hi+lo planes, 16 mantissa
 * bits total), K ordered k = tap*64 + ch, pre-tiled per (m-tile, K-step).
 * Ahi/Alo[((mt*18 + s)*128 + i)*32 + kk], m = mt*128+i, tap r = s>>1,
 * ch c = (s&1)*32 + kk.
 * ===================================================================== */
__global__ __launch_bounds__(256) void lte_prep_w(
    const float* __restrict__ cw, const float* __restrict__ fw,
    u16* __restrict__ Ahi, u16* __restrict__ Alo) {
  int id = blockIdx.x * 256 + threadIdx.x;
  if (id >= WELEM) return;
  int kk = id & 31;
  int i  = (id >> 5) & 127;
  int t2 = id >> 12;            /* mt*18 + s */
  int mt = t2 / 18;
  int s  = t2 - mt * 18;
  int m  = mt * 128 + i;
  int r  = s >> 1;
  int c  = ((s & 1) << 5) + kk;
  const float* src = (m < HID) ? cw : fw;
  float x = src[(m & 255) * KTOT + c * 9 + r];
  u16 hi = f2bf(x);
  u16 lo = f2bf(x - bf2f(hi));
  Ahi[id] = hi;
  Alo[id] = lo;
}

/* =====================================================================
 * Kernel 2: implicit-im2col GEMM, Y = W(512x576) * patches(576x16384)
 * per batch. Split-bf16 MFMA (acc += ah*bh + ah*bl + al*bh) gives
 * ~fp32-grade products (lo*lo ~ 2^-18 dropped). 128x128 tile, 4 waves,
 * 4x4 16x16x32 fragments/wave. Output pixel-major YT[b][p][512] (+bias)
 * so the sampler's corner gathers are contiguous.
 * ===================================================================== */
template <typename OutT>
__global__ __launch_bounds__(256) void lte_conv_gemm(
    const float* __restrict__ inp, const u16* __restrict__ Ahi_g,
    const u16* __restrict__ Alo_g,
    const float* __restrict__ coef_b, const float* __restrict__ freq_b,
    OutT* __restrict__ YT) {
  /* [row][k] tiles, stride 40 shorts (80 B: keeps 16B align for b128,
     spreads fragment rows over banks). 4 x 10240 B = 40 KB LDS. */
  __shared__ u16 Ah[128 * 40];
  __shared__ u16 Bh[128 * 40];
  __shared__ u16 Al[128 * 40];
  __shared__ u16 Bl[128 * 40];

  const int t  = threadIdx.x;
  const int bx = blockIdx.x;     /* image row y; pixel tile = [bx*128, +128) */
  const int mt = blockIdx.y;     /* m tile (0..3) */
  const int bb = blockIdx.z;     /* batch */
  const int l  = t & 63;
  const int w  = t >> 6;
  const int wr = w >> 1, wc = w & 1;
  const int lm = l & 15;
  const int ko = (l >> 4) * 8;

  f32x4 acc[4][4] = {};

  const u16* Atile_h = Ahi_g + (size_t)(mt * 18) * 4096;
  const u16* Atile_l = Alo_g + (size_t)(mt * 18) * 4096;
  const int ao1 = t * 8;          /* shorts, rows 0..63 */
  const int ao2 = 2048 + t * 8;   /* rows 64..127 */
  const int ad1 = (ao1 >> 5) * 40 + (ao1 & 31);
  const int ad2 = (ao2 >> 5) * 40 + (ao2 & 31);
  const int px  = t & 127;
  const int hf  = t >> 7;         /* which 16-channel half */

  for (int s = 0; s < 18; ++s) {
    const int r  = s >> 1;
    const int cb = (s & 1) << 5;
    const int ky = r / 3, kx = r - ky * 3;
    __syncthreads();
    { /* A stage: linear copies of pre-tiled hi/lo planes */
      const u16* ath = Atile_h + s * 4096;
      const u16* atl = Atile_l + s * 4096;
      *(bf16x8*)&Ah[ad1] = *(const bf16x8*)(ath + ao1);
      *(bf16x8*)&Ah[ad2] = *(const bf16x8*)(ath + ao2);
      *(bf16x8*)&Al[ad1] = *(const bf16x8*)(atl + ao1);
      *(bf16x8*)&Al[ad2] = *(const bf16x8*)(atl + ao2);
    }
    { /* B stage: 16 channels x 1 pixel per thread, shifted row, zero-pad,
         split each f32 into hi+lo bf16 */
      const int y1 = bx + ky - 1;
      const int x1 = px + kx - 1;
      float v[16];
      if ((unsigned)y1 < 128u) {
        const bool okx = (unsigned)x1 < 128u;
        const float* ip = inp + (((size_t)(bb * CIN + cb + hf * 16) * HH + y1) * WW + x1);
#pragma unroll
        for (int k2 = 0; k2 < 16; ++k2) v[k2] = okx ? ip[k2 * NPIX] : 0.f;
      } else {
#pragma unroll
        for (int k2 = 0; k2 < 16; ++k2) v[k2] = 0.f;
      }
#pragma unroll
      for (int q = 0; q < 8; ++q) {
        u16 h0 = f2bf(v[2 * q]), h1 = f2bf(v[2 * q + 1]);
        u16 l0 = f2bf(v[2 * q] - bf2f(h0)), l1 = f2bf(v[2 * q + 1] - bf2f(h1));
        *(unsigned*)&Bh[px * 40 + hf * 16 + 2 * q] = (unsigned)h0 | ((unsigned)h1 << 16);
        *(unsigned*)&Bl[px * 40 + hf * 16 + 2 * q] = (unsigned)l0 | ((unsigned)l1 << 16);
      }
    }
    __syncthreads();
    bf16x8 afh[4], bgh[4], afl[4], bgl[4];
#pragma unroll
    for (int mi = 0; mi < 4; ++mi) {
      afh[mi] = *(const bf16x8*)&Ah[(wr * 64 + mi * 16 + lm) * 40 + ko];
      afl[mi] = *(const bf16x8*)&Al[(wr * 64 + mi * 16 + lm) * 40 + ko];
    }
#pragma unroll
    for (int ni = 0; ni < 4; ++ni) {
      bgh[ni] = *(const bf16x8*)&Bh[(wc * 64 + ni * 16 + lm) * 40 + ko];
      bgl[ni] = *(const bf16x8*)&Bl[(wc * 64 + ni * 16 + lm) * 40 + ko];
    }
#pragma unroll
    for (int mi = 0; mi < 4; ++mi)
#pragma unroll
      for (int ni = 0; ni < 4; ++ni) {
        acc[mi][ni] = __builtin_amdgcn_mfma_f32_16x16x32_bf16(afh[mi], bgh[ni], acc[mi][ni], 0, 0, 0);
        acc[mi][ni] = __builtin_amdgcn_mfma_f32_16x16x32_bf16(afh[mi], bgl[ni], acc[mi][ni], 0, 0, 0);
        acc[mi][ni] = __builtin_amdgcn_mfma_f32_16x16x32_bf16(afl[mi], bgh[ni], acc[mi][ni], 0, 0, 0);
      }
  }

  /* epilogue: +bias, store pixel-major YT[b][p][512] */
  const float* bias = (mt < 2) ? (coef_b + mt * 128) : (freq_b + (mt - 2) * 128);
  const int rj = (l >> 4) * 4;
#pragma unroll
  for (int mi = 0; mi < 4; ++mi) {
    const int bm = wr * 64 + mi * 16 + rj;
    const float b0 = bias[bm], b1 = bias[bm + 1], b2 = bias[bm + 2], b3 = bias[bm + 3];
#pragma unroll
    for (int ni = 0; ni < 4; ++ni) {
      const int p = bx * 128 + wc * 64 + ni * 16 + lm;
      size_t off = ((size_t)(bb * NPIX + p)) * 512 + mt * 128 + bm;
      f32x4 v = acc[mi][ni];
      store4(&YT[off], v[0] + b0, v[1] + b1, v[2] + b2, v[3] + b3);
    }
  }
}

/* =====================================================================
 * Kernel 3: 4-corner nearest sample + sin/cos modulation.
 * 128 threads/block, 16 queries/block. Thread j owns channels j (cos)
 * and j+128 (sin) -> freq pair is one contiguous load, no exchange.
 * Results staged in LDS [256][17] then written channel-major, coalesced.
 * Index path bit-matches the reference f32 trace (RNE rounding, exact
 * pow2 scalings).
 * ===================================================================== */
template <typename T>
__global__ __launch_bounds__(128) void lte_sample(
    const T* __restrict__ YT, const float* __restrict__ coord,
    const float* __restrict__ cell, const float* __restrict__ phase_w,
    float* __restrict__ out) {
  __shared__ float lout[256 * 17];
  const int j     = threadIdx.x;          /* 0..127 */
  const int q0    = blockIdx.x * 16;      /* global over B*Q */
  const int b     = q0 >> 14;
  const int q0loc = q0 & (NPIX - 1);
  const float pw0 = phase_w[2 * j], pw1 = phase_w[2 * j + 1];
  const T* Yb = YT + ((size_t)b * NPIX) * 512;

  for (int qi = 0; qi < 16; ++qi) {
    const int qg = q0 + qi;
    const float c0  = coord[2 * qg], c1 = coord[2 * qg + 1];
    const float ce0 = cell[2 * qg],  ce1 = cell[2 * qg + 1];
    const float ph  = (ce0 * 128.0f) * pw0 + (ce1 * 128.0f) * pw1;
    float accC = 0.f, accS = 0.f, tot = 0.f, a3 = 0.f;
#pragma unroll
    for (int ci = 0; ci < 4; ++ci) {     /* (vx,vy): (-,-),(-,+),(+,-),(+,+) */
      const float s0 = (ci & 2) ? SHP : SHM;
      const float s1 = (ci & 1) ? SHP : SHM;
      float cx = fminf(fmaxf(c0 + s0, CLO), CHI);
      float cy = fminf(fmaxf(c1 + s1, CLO), CHI);
      float ty = ((cx + 1.0f) * 128.0f - 1.0f) * 0.5f;
      float tx = ((cy + 1.0f) * 128.0f - 1.0f) * 0.5f;
      float fy = fminf(fmaxf(rintf(ty), 0.f), 127.f);   /* round half-even */
      float fx = fminf(fmaxf(rintf(tx), 0.f), 127.f);
      int iy = (int)fy, ix = (int)fx;
      float qcy = -1.0f + (2.0f * fy + 1.0f) * (1.0f / 128.0f);
      float qcx = -1.0f + (2.0f * fx + 1.0f) * (1.0f / 128.0f);
      float rel0 = (c0 - qcy) * 128.0f;
      float rel1 = (c1 - qcx) * 128.0f;
      float ar = fabsf(rel0 * rel1);
      tot += ar + 1e-9f;
      if (ci == 3) a3 = ar;
      const T* bp = Yb + ((size_t)(iy * 128 + ix)) * 512;
      float coefA = ldv(bp + j);          /* coef channel j   */
      float coefB = ldv(bp + 128 + j);    /* coef channel j+128 */
      float f0, f1;
      ldpair(bp + 256 + 2 * j, f0, f1);   /* freq pair (2j, 2j+1) */
      float f = f0 * rel0 + f1 * rel1 + ph;
      float ang = PIF * f;
      accC += coefA * __cosf(ang);
      accS += coefB * __sinf(ang);
    }
    const float wgt = a3 / tot;
    lout[j * 17 + qi]         = accC * wgt;
    lout[(j + 128) * 17 + qi] = accS * wgt;
  }
  __syncthreads();
#pragma unroll
  for (int pass = 0; pass < 8; ++pass) {
    int c  = pass * 32 + (j >> 2);
    int qf = (j & 3) * 4;
    float4 v;
    v.x = lout[c * 17 + qf];     v.y = lout[c * 17 + qf + 1];
    v.z = lout[c * 17 + qf + 2]; v.w = lout[c * 17 + qf + 3];
    *(float4*)(out + (((size_t)(b * 256 + c)) << 14) + q0loc + qf) = v;
  }
}

extern "C" void kernel_launch(void* const* d_in, const int* in_sizes, int n_in,
                              void* d_out, int out_size, void* d_ws, size_t ws_size,
                              hipStream_t stream) {
  const float* inp     = (const float*)d_in[0];
  const float* coord   = (const float*)d_in[1];
  const float* cell    = (const float*)d_in[2];
  const float* coef_w  = (const float*)d_in[3];
  const float* coef_b  = (const float*)d_in[4];
  const float* freq_w  = (const float*)d_in[5];
  const float* freq_b  = (const float*)d_in[6];
  const float* phase_w = (const float*)d_in[7];
  float* out = (float*)d_out;

  u16* Ahi = (u16*)d_ws;
  u16* Alo = Ahi + WELEM;
  const size_t offY = (size_t)WELEM * 2 * 2;     /* 1,179,648 B, 16B aligned */
  char* yraw = (char*)d_ws + offY;
  const size_t f32Need = offY + (size_t)NB * NPIX * 512 * 4;
  const bool f32path = (ws_size >= f32Need);

  lte_prep_w<<<dim3(1152), dim3(256), 0, stream>>>(coef_w, freq_w, Ahi, Alo);
  if (f32path) {
    float* YT = (float*)yraw;
    lte_conv_gemm<float><<<dim3(128, 4, 4), dim3(256), 0, stream>>>(inp, Ahi, Alo, coef_b, freq_b, YT);
    lte_sample<float><<<dim3(4096), dim3(128), 0, stream>>>(YT, coord, cell, phase_w, out);
  } else {
    short* YT = (short*)yraw;
    lte_conv_gemm<short><<<dim3(128, 4, 4), dim3(256), 0, stream>>>(inp, Ahi, Alo, coef_b, freq_b, YT);
    lte_sample<short><<<dim3(4096), dim3(128), 0, stream>>>(YT, coord, cell, phase_w, out);
  }
}

// Round 3
// 138.771 us; speedup vs baseline: 1.7614x; 1.7614x over previous
//
#include <hip/hip_runtime.h>

typedef unsigned short u16;
typedef _Float16 f16;

#define CIN   64
#define HH    128
#define WW    128
#define NPIX  16384   /* HH*WW */
#define HID   256
#define MTOT  512     /* coef(256) + freq(256) stacked */
#define KTOT  576     /* 64 ch * 9 taps */
#define NB    4
#define WELEM 294912  /* MTOT*KTOT */

/* index-path constants: must bit-match the f32 trace of the reference */
#define SHM  ((float)(-0.0078125 + 1e-6))
#define SHP  ((float)( 0.0078125 + 1e-6))
#define CLO  ((float)(-1.0 + 1e-6))
#define CHI  ((float)( 1.0 - 1e-6))
#define PIF  3.14159265358979323846f

#define QSCL  1024.0f          /* int16 fixed-point scale for YT */
#define QISCL (1.0f / 1024.0f)

using f32x4 = __attribute__((ext_vector_type(4))) float;
using f16x8 = __attribute__((ext_vector_type(8))) _Float16;

/* ---- int16 fixed-point YT helpers ---- */
__device__ __forceinline__ float ldq(const short* p) { return (float)(*p) * QISCL; }
__device__ __forceinline__ void ldqpair(const short* p, float& a, float& b) {
  int u = *(const int*)p;
  a = (float)((short)(u & 0xFFFF)) * QISCL;
  b = (float)((short)(u >> 16)) * QISCL;
}
__device__ __forceinline__ unsigned packq(float a, float b) {
  float fa = fminf(fmaxf(a * QSCL, -32767.f), 32767.f);
  float fb = fminf(fmaxf(b * QSCL, -32767.f), 32767.f);
  int ia = (int)rintf(fa), ib = (int)rintf(fb);
  return ((unsigned)(unsigned short)(short)ia) | (((unsigned)(unsigned short)(short)ib) << 16);
}
__device__ __forceinline__ void storeq4(short* p, float a, float b, float c, float d) {
  uint2 v; v.x = packq(a, b); v.y = packq(c, d);
  *(uint2*)p = v;
}

/* =====================================================================
 * Kernel 1: repack conv weights -> fp16, K ordered k = tap*64 + ch,
 * pre-tiled per (m-tile, K-step): Awp[((mt*18+s)*128 + i)*32 + kk],
 * m = mt*128+i, tap r = s>>1, ch c = (s&1)*32 + kk.  (layout validated R2)
 * ===================================================================== */
__global__ __launch_bounds__(256) void lte_prep_w(
    const float* __restrict__ cw, const float* __restrict__ fw,
    f16* __restrict__ Awp) {
  int id = blockIdx.x * 256 + threadIdx.x;
  if (id >= WELEM) return;
  int kk = id & 31;
  int i  = (id >> 5) & 127;
  int t2 = id >> 12;            /* mt*18 + s */
  int mt = t2 / 18;
  int s  = t2 - mt * 18;
  int m  = mt * 128 + i;
  int r  = s >> 1;
  int c  = ((s & 1) << 5) + kk;
  const float* src = (m < HID) ? cw : fw;
  Awp[id] = (f16)src[(m & 255) * KTOT + c * 9 + r];
}

/* =====================================================================
 * Kernel 1b: transpose input NCHW f32 -> pixel-major fp16 [b*16384+p][64].
 * Reads coalesced per channel plane; writes 128B contiguous per pixel.
 * ===================================================================== */
__global__ __launch_bounds__(256) void lte_prep_x(
    const float* __restrict__ inp, f16* __restrict__ xp) {
  int id = blockIdx.x * 256 + threadIdx.x;   /* pixel id over B*NPIX */
  int b  = id >> 14;
  int p  = id & (NPIX - 1);
  const float* ip = inp + (size_t)b * CIN * NPIX + p;
  f16* op = xp + (size_t)id * 64;
#pragma unroll
  for (int q = 0; q < 8; ++q) {
    f16x8 v;
#pragma unroll
    for (int k = 0; k < 8; ++k) v[k] = (f16)ip[(q * 8 + k) * NPIX];
    *(f16x8*)(op + q * 8) = v;
  }
}

/* =====================================================================
 * Kernel 2: implicit-im2col GEMM, Y = W(512x576) * patches(576x16384)
 * per batch, fp16 MFMA 16x16x32, 128x128 tile, 4 waves (2x2), 4x4 frags.
 * All f32->f16 conversion pre-hoisted: staging is pure vector copy.
 * Output pixel-major int16 YT[b][p][512] (+bias), scale 1024.
 * ===================================================================== */
__global__ __launch_bounds__(256) void lte_conv_gemm(
    const f16* __restrict__ xp, const f16* __restrict__ Awp,
    const float* __restrict__ coef_b, const float* __restrict__ freq_b,
    short* __restrict__ YT) {
  /* [row][k] tiles, stride 40 halfs (80 B: 16B-aligned b128 rows). 20KB. */
  __shared__ f16 As[128 * 40];
  __shared__ f16 Bs[128 * 40];

  const int t  = threadIdx.x;
  const int bx = blockIdx.x;     /* image row y; pixel tile = [bx*128,+128) */
  const int mt = blockIdx.y;     /* m tile (0..3) */
  const int bb = blockIdx.z;     /* batch */
  const int l  = t & 63;
  const int w  = t >> 6;
  const int wr = w >> 1, wc = w & 1;
  const int lm = l & 15;
  const int ko = (l >> 4) * 8;

  f32x4 acc[4][4] = {};

  const f16* Atile = Awp + (size_t)(mt * 18) * 4096;
  const int ao = t * 16;                       /* halfs; 256*16 = full tile */
  const int ad = (ao >> 5) * 40 + (ao & 31);
  const int px = t & 127;
  const int hf = t >> 7;                       /* 16-ch half within K-step */

  for (int s = 0; s < 18; ++s) {
    const int r  = s >> 1;
    const int cb = (s & 1) << 5;
    const int ky = r / 3, kx = r - ky * 3;
    __syncthreads();
    { /* A stage: linear 8KB copy of pre-tiled fp16 plane */
      const f16* at = Atile + s * 4096 + ao;
      *(f16x8*)&As[ad]     = *(const f16x8*)(at);
      *(f16x8*)&As[ad + 8] = *(const f16x8*)(at + 8);
    }
    { /* B stage: 32B contiguous per thread from pixel-major fp16 input */
      const int y1 = bx + ky - 1;
      const int x1 = px + kx - 1;
      f16x8 b0 = {}, b1 = {};
      if ((unsigned)y1 < 128u && (unsigned)x1 < 128u) {
        const f16* bp = xp + ((((size_t)(bb << 14)) + (y1 << 7) + x1) << 6) + cb + hf * 16;
        b0 = *(const f16x8*)bp;
        b1 = *(const f16x8*)(bp + 8);
      }
      *(f16x8*)&Bs[px * 40 + hf * 16]     = b0;
      *(f16x8*)&Bs[px * 40 + hf * 16 + 8] = b1;
    }
    __syncthreads();
    f16x8 af[4], bg[4];
#pragma unroll
    for (int mi = 0; mi < 4; ++mi)
      af[mi] = *(const f16x8*)&As[(wr * 64 + mi * 16 + lm) * 40 + ko];
#pragma unroll
    for (int ni = 0; ni < 4; ++ni)
      bg[ni] = *(const f16x8*)&Bs[(wc * 64 + ni * 16 + lm) * 40 + ko];
#pragma unroll
    for (int mi = 0; mi < 4; ++mi)
#pragma unroll
      for (int ni = 0; ni < 4; ++ni)
        acc[mi][ni] = __builtin_amdgcn_mfma_f32_16x16x32_f16(af[mi], bg[ni], acc[mi][ni], 0, 0, 0);
  }

  /* epilogue: +bias, quantize, store pixel-major YT[b][p][512] */
  const float* bias = (mt < 2) ? (coef_b + mt * 128) : (freq_b + (mt - 2) * 128);
  const int rj = (l >> 4) * 4;
#pragma unroll
  for (int mi = 0; mi < 4; ++mi) {
    const int bm = wr * 64 + mi * 16 + rj;
    const float b0 = bias[bm], b1 = bias[bm + 1], b2 = bias[bm + 2], b3 = bias[bm + 3];
#pragma unroll
    for (int ni = 0; ni < 4; ++ni) {
      const int p = bx * 128 + wc * 64 + ni * 16 + lm;
      size_t off = ((size_t)(bb * NPIX + p)) * 512 + mt * 128 + bm;
      f32x4 v = acc[mi][ni];
      storeq4(&YT[off], v[0] + b0, v[1] + b1, v[2] + b2, v[3] + b3);
    }
  }
}

/* =====================================================================
 * Kernel 3: 4-corner nearest sample + sin/cos modulation (int16 YT).
 * 128 threads/block, 16 queries/block. Thread j owns channels j (cos)
 * and j+128 (sin); freq pair (2j,2j+1) is one 4B load. Results staged
 * in LDS [256][17] then written channel-major, coalesced. Index path
 * bit-matches the reference f32 trace.
 * ===================================================================== */
__global__ __launch_bounds__(128) void lte_sample(
    const short* __restrict__ YT, const float* __restrict__ coord,
    const float* __restrict__ cell, const float* __restrict__ phase_w,
    float* __restrict__ out) {
  __shared__ float lout[256 * 17];
  const int j     = threadIdx.x;          /* 0..127 */
  const int q0    = blockIdx.x * 16;      /* global over B*Q */
  const int b     = q0 >> 14;
  const int q0loc = q0 & (NPIX - 1);
  const float pw0 = phase_w[2 * j], pw1 = phase_w[2 * j + 1];
  const short* Yb = YT + ((size_t)b * NPIX) * 512;

  for (int qi = 0; qi < 16; ++qi) {
    const int qg = q0 + qi;
    const float c0  = coord[2 * qg], c1 = coord[2 * qg + 1];
    const float ce0 = cell[2 * qg],  ce1 = cell[2 * qg + 1];
    const float ph  = (ce0 * 128.0f) * pw0 + (ce1 * 128.0f) * pw1;
    float accC = 0.f, accS = 0.f, tot = 0.f, a3 = 0.f;
#pragma unroll
    for (int ci = 0; ci < 4; ++ci) {     /* (vx,vy): (-,-),(-,+),(+,-),(+,+) */
      const float s0 = (ci & 2) ? SHP : SHM;
      const float s1 = (ci & 1) ? SHP : SHM;
      float cx = fminf(fmaxf(c0 + s0, CLO), CHI);
      float cy = fminf(fmaxf(c1 + s1, CLO), CHI);
      float ty = ((cx + 1.0f) * 128.0f - 1.0f) * 0.5f;
      float tx = ((cy + 1.0f) * 128.0f - 1.0f) * 0.5f;
      float fy = fminf(fmaxf(rintf(ty), 0.f), 127.f);   /* round half-even */
      float fx = fminf(fmaxf(rintf(tx), 0.f), 127.f);
      int iy = (int)fy, ix = (int)fx;
      float qcy = -1.0f + (2.0f * fy + 1.0f) * (1.0f / 128.0f);
      float qcx = -1.0f + (2.0f * fx + 1.0f) * (1.0f / 128.0f);
      float rel0 = (c0 - qcy) * 128.0f;
      float rel1 = (c1 - qcx) * 128.0f;
      float ar = fabsf(rel0 * rel1);
      tot += ar + 1e-9f;
      if (ci == 3) a3 = ar;
      const short* bp = Yb + ((size_t)(iy * 128 + ix)) * 512;
      float coefA = ldq(bp + j);          /* coef channel j    */
      float coefB = ldq(bp + 128 + j);    /* coef channel j+128 */
      float f0, f1;
      ldqpair(bp + 256 + 2 * j, f0, f1);  /* freq pair (2j,2j+1) */
      float f = f0 * rel0 + f1 * rel1 + ph;
      float ang = PIF * f;
      accC += coefA * __cosf(ang);
      accS += coefB * __sinf(ang);
    }
    const float wgt = a3 / tot;
    lout[j * 17 + qi]         = accC * wgt;
    lout[(j + 128) * 17 + qi] = accS * wgt;
  }
  __syncthreads();
#pragma unroll
  for (int pass = 0; pass < 8; ++pass) {
    int c  = pass * 32 + (j >> 2);
    int qf = (j & 3) * 4;
    float4 v;
    v.x = lout[c * 17 + qf];     v.y = lout[c * 17 + qf + 1];
    v.z = lout[c * 17 + qf + 2]; v.w = lout[c * 17 + qf + 3];
    *(float4*)(out + (((size_t)(b * 256 + c)) << 14) + q0loc + qf) = v;
  }
}

extern "C" void kernel_launch(void* const* d_in, const int* in_sizes, int n_in,
                              void* d_out, int out_size, void* d_ws, size_t ws_size,
                              hipStream_t stream) {
  const float* inp     = (const float*)d_in[0];
  const float* coord   = (const float*)d_in[1];
  const float* cell    = (const float*)d_in[2];
  const float* coef_w  = (const float*)d_in[3];
  const float* coef_b  = (const float*)d_in[4];
  const float* freq_w  = (const float*)d_in[5];
  const float* freq_b  = (const float*)d_in[6];
  const float* phase_w = (const float*)d_in[7];
  float* out = (float*)d_out;

  /* ws layout: Awp fp16 (0.59MB) | xp fp16 (8.39MB) | YT int16 (67.1MB).
     Total 76.1MB; R2 proved ws >= 135MB. All offsets 16B-aligned. */
  f16* Awp = (f16*)d_ws;
  f16* xp  = (f16*)((char*)d_ws + (size_t)WELEM * 2);
  short* YT = (short*)((char*)d_ws + (size_t)WELEM * 2 + (size_t)NB * NPIX * 64 * 2);

  lte_prep_w<<<dim3(1152), dim3(256), 0, stream>>>(coef_w, freq_w, Awp);
  lte_prep_x<<<dim3(256),  dim3(256), 0, stream>>>(inp, xp);
  lte_conv_gemm<<<dim3(128, 4, 4), dim3(256), 0, stream>>>(xp, Awp, coef_b, freq_b, YT);
  lte_sample<<<dim3(4096), dim3(128), 0, stream>>>(YT, coord, cell, phase_w, out);
}

// Round 4
// 137.141 us; speedup vs baseline: 1.7823x; 1.0119x over previous
//
#include <hip/hip_runtime.h>

typedef unsigned short u16;
typedef _Float16 f16;

#define CIN   64
#define HH    128
#define WW    128
#define NPIX  16384   /* HH*WW */
#define HID   256
#define MTOT  512     /* coef(256) + freq(256) stacked */
#define KTOT  576     /* 64 ch * 9 taps */
#define NB    4
#define WELEM 294912  /* MTOT*KTOT */

/* index-path constants: must bit-match the f32 trace of the reference */
#define SHM  ((float)(-0.0078125 + 1e-6))
#define SHP  ((float)( 0.0078125 + 1e-6))
#define CLO  ((float)(-1.0 + 1e-6))
#define CHI  ((float)( 1.0 - 1e-6))
#define PIF  3.14159265358979323846f

#define QSCL  1024.0f          /* int16 fixed-point scale for YT */
#define QISCL (1.0f / 1024.0f)

#define LDSW  72               /* LDS row stride in halfs: 144B -> uniform
                                  2-way bank conflicts only (free) */

using f32x4 = __attribute__((ext_vector_type(4))) float;
using f16x8 = __attribute__((ext_vector_type(8))) _Float16;

/* ---- int16 fixed-point YT helpers ---- */
__device__ __forceinline__ float ldq(const short* p) { return (float)(*p) * QISCL; }
__device__ __forceinline__ void ldqpair(const short* p, float& a, float& b) {
  int u = *(const int*)p;
  a = (float)((short)(u & 0xFFFF)) * QISCL;
  b = (float)((short)(u >> 16)) * QISCL;
}
__device__ __forceinline__ unsigned packq(float a, float b) {
  float fa = fminf(fmaxf(a * QSCL, -32767.f), 32767.f);
  float fb = fminf(fmaxf(b * QSCL, -32767.f), 32767.f);
  int ia = (int)rintf(fa), ib = (int)rintf(fb);
  return ((unsigned)(unsigned short)(short)ia) | (((unsigned)(unsigned short)(short)ib) << 16);
}
__device__ __forceinline__ void storeq4(short* p, float a, float b, float c, float d) {
  uint2 v; v.x = packq(a, b); v.y = packq(c, d);
  *(uint2*)p = v;
}

/* =====================================================================
 * Kernel 1: repack conv weights -> fp16, K ordered k = tap*64 + ch,
 * pre-tiled per (m-tile, BK=64 step): Awp[((mt*9+s)*128 + i)*64 + kk],
 * m = mt*128+i, tap = s, ch = kk.
 * ===================================================================== */
__global__ __launch_bounds__(256) void lte_prep_w(
    const float* __restrict__ cw, const float* __restrict__ fw,
    f16* __restrict__ Awp) {
  int id = blockIdx.x * 256 + threadIdx.x;
  if (id >= WELEM) return;
  int kk = id & 63;
  int i  = (id >> 6) & 127;
  int t2 = id >> 13;            /* mt*9 + s */
  int mt = t2 / 9;
  int s  = t2 - mt * 9;
  int m  = mt * 128 + i;
  const float* src = (m < HID) ? cw : fw;
  Awp[id] = (f16)src[(m & 255) * KTOT + kk * 9 + s];
}

/* =====================================================================
 * Kernel 1b: transpose input NCHW f32 -> pixel-major fp16 [b*16384+p][64].
 * ===================================================================== */
__global__ __launch_bounds__(256) void lte_prep_x(
    const float* __restrict__ inp, f16* __restrict__ xp) {
  int id = blockIdx.x * 256 + threadIdx.x;   /* pixel id over B*NPIX */
  int b  = id >> 14;
  int p  = id & (NPIX - 1);
  const float* ip = inp + (size_t)b * CIN * NPIX + p;
  f16* op = xp + (size_t)id * 64;
#pragma unroll
  for (int q = 0; q < 8; ++q) {
    f16x8 v;
#pragma unroll
    for (int k = 0; k < 8; ++k) v[k] = (f16)ip[(q * 8 + k) * NPIX];
    *(f16x8*)(op + q * 8) = v;
  }
}

/* =====================================================================
 * Kernel 2: implicit-im2col GEMM, Y = W(512x576) * patches(576x16384)
 * per batch, fp16 MFMA 16x16x32. 128x128 tile, 4 waves (2x2), 4x4 frags,
 * BK=64 (one 3x3 tap x 64ch per step, 9 steps, 32 MFMA/wave/step).
 * 2-phase register-prefetch: issue next-step global loads before compute,
 * ds_write after the post-compute barrier (HBM latency hides under MFMA).
 * Output pixel-major int16 YT[b][p][512] (+bias), scale 1024.
 * ===================================================================== */
__global__ __launch_bounds__(256) void lte_conv_gemm(
    const f16* __restrict__ xp, const f16* __restrict__ Awp,
    const float* __restrict__ coef_b, const float* __restrict__ freq_b,
    short* __restrict__ YT) {
  __shared__ f16 As[128 * LDSW];   /* 18432 B */
  __shared__ f16 Bs[128 * LDSW];   /* 18432 B */

  const int t  = threadIdx.x;
  const int bx = blockIdx.x;     /* image row y; pixel tile = [bx*128,+128) */
  const int mt = blockIdx.y;     /* m tile (0..3) */
  const int bb = blockIdx.z;     /* batch */
  const int l  = t & 63;
  const int w  = t >> 6;
  const int wr = w >> 1, wc = w & 1;
  const int lm = l & 15;
  const int ko = (l >> 4) * 8;

  f32x4 acc[4][4] = {};

  const f16* Atile = Awp + (size_t)(mt * 9) * 8192;
  /* A stage: thread t owns 32 halfs (64B): row t>>1, half (t&1) */
  const int aoff_lds = (t >> 1) * LDSW + (t & 1) * 32;
  /* B stage: thread t owns pixel px, 32-ch half hf */
  const int px = t & 127;
  const int hf = t >> 7;
  const int boff_lds = px * LDSW + hf * 32;
  const size_t brec = ((size_t)(bb << 14) << 6) + hf * 32;  /* + (y*128+x)*64 */

  f16x8 ra[4], rb[4];

#define LOAD_STEP(s_)                                                        \
  {                                                                          \
    const int s__ = (s_);                                                    \
    const f16* at = Atile + s__ * 8192 + t * 32;                             \
    ra[0] = *(const f16x8*)(at);                                             \
    ra[1] = *(const f16x8*)(at + 8);                                         \
    ra[2] = *(const f16x8*)(at + 16);                                        \
    ra[3] = *(const f16x8*)(at + 24);                                        \
    const int ky = s__ / 3, kx = s__ - 3 * (s__ / 3);                        \
    const int y1 = bx + ky - 1;                                              \
    const int x1 = px + kx - 1;                                              \
    rb[0] = (f16x8){}; rb[1] = (f16x8){}; rb[2] = (f16x8){}; rb[3] = (f16x8){}; \
    if ((unsigned)y1 < 128u && (unsigned)x1 < 128u) {                        \
      const f16* bp = xp + brec + (((size_t)(y1 << 7) + x1) << 6);           \
      rb[0] = *(const f16x8*)(bp);                                           \
      rb[1] = *(const f16x8*)(bp + 8);                                       \
      rb[2] = *(const f16x8*)(bp + 16);                                      \
      rb[3] = *(const f16x8*)(bp + 24);                                      \
    }                                                                        \
  }

#define WRITE_STEP                                                           \
  {                                                                          \
    *(f16x8*)&As[aoff_lds]      = ra[0];                                     \
    *(f16x8*)&As[aoff_lds + 8]  = ra[1];                                     \
    *(f16x8*)&As[aoff_lds + 16] = ra[2];                                     \
    *(f16x8*)&As[aoff_lds + 24] = ra[3];                                     \
    *(f16x8*)&Bs[boff_lds]      = rb[0];                                     \
    *(f16x8*)&Bs[boff_lds + 8]  = rb[1];                                     \
    *(f16x8*)&Bs[boff_lds + 16] = rb[2];                                     \
    *(f16x8*)&Bs[boff_lds + 24] = rb[3];                                     \
  }

  LOAD_STEP(0)
  WRITE_STEP
  __syncthreads();

  for (int s = 0; s < 9; ++s) {
    if (s < 8) LOAD_STEP(s + 1)      /* issue early: latency hides under MFMA */
#pragma unroll
    for (int ks = 0; ks < 2; ++ks) {
      f16x8 af[4], bg[4];
#pragma unroll
      for (int mi = 0; mi < 4; ++mi)
        af[mi] = *(const f16x8*)&As[(wr * 64 + mi * 16 + lm) * LDSW + ks * 32 + ko];
#pragma unroll
      for (int ni = 0; ni < 4; ++ni)
        bg[ni] = *(const f16x8*)&Bs[(wc * 64 + ni * 16 + lm) * LDSW + ks * 32 + ko];
#pragma unroll
      for (int mi = 0; mi < 4; ++mi)
#pragma unroll
        for (int ni = 0; ni < 4; ++ni)
          acc[mi][ni] = __builtin_amdgcn_mfma_f32_16x16x32_f16(af[mi], bg[ni], acc[mi][ni], 0, 0, 0);
    }
    __syncthreads();
    if (s < 8) {
      WRITE_STEP
      __syncthreads();
    }
  }

  /* epilogue: +bias, quantize, store pixel-major YT[b][p][512] */
  const float* bias = (mt < 2) ? (coef_b + mt * 128) : (freq_b + (mt - 2) * 128);
  const int rj = (l >> 4) * 4;
#pragma unroll
  for (int mi = 0; mi < 4; ++mi) {
    const int bm = wr * 64 + mi * 16 + rj;
    const float b0 = bias[bm], b1 = bias[bm + 1], b2 = bias[bm + 2], b3 = bias[bm + 3];
#pragma unroll
    for (int ni = 0; ni < 4; ++ni) {
      const int p = bx * 128 + wc * 64 + ni * 16 + lm;
      size_t off = ((size_t)(bb * NPIX + p)) * 512 + mt * 128 + bm;
      f32x4 v = acc[mi][ni];
      storeq4(&YT[off], v[0] + b0, v[1] + b1, v[2] + b2, v[3] + b3);
    }
  }
}

/* =====================================================================
 * Kernel 3: 4-corner nearest sample + sin/cos modulation (int16 YT).
 * Validated bit-exact index path — unchanged from R3.
 * ===================================================================== */
__global__ __launch_bounds__(128) void lte_sample(
    const short* __restrict__ YT, const float* __restrict__ coord,
    const float* __restrict__ cell, const float* __restrict__ phase_w,
    float* __restrict__ out) {
  __shared__ float lout[256 * 17];
  const int j     = threadIdx.x;          /* 0..127 */
  const int q0    = blockIdx.x * 16;      /* global over B*Q */
  const int b     = q0 >> 14;
  const int q0loc = q0 & (NPIX - 1);
  const float pw0 = phase_w[2 * j], pw1 = phase_w[2 * j + 1];
  const short* Yb = YT + ((size_t)b * NPIX) * 512;

  for (int qi = 0; qi < 16; ++qi) {
    const int qg = q0 + qi;
    const float c0  = coord[2 * qg], c1 = coord[2 * qg + 1];
    const float ce0 = cell[2 * qg],  ce1 = cell[2 * qg + 1];
    const float ph  = (ce0 * 128.0f) * pw0 + (ce1 * 128.0f) * pw1;
    float accC = 0.f, accS = 0.f, tot = 0.f, a3 = 0.f;
#pragma unroll
    for (int ci = 0; ci < 4; ++ci) {     /* (vx,vy): (-,-),(-,+),(+,-),(+,+) */
      const float s0 = (ci & 2) ? SHP : SHM;
      const float s1 = (ci & 1) ? SHP : SHM;
      float cx = fminf(fmaxf(c0 + s0, CLO), CHI);
      float cy = fminf(fmaxf(c1 + s1, CLO), CHI);
      float ty = ((cx + 1.0f) * 128.0f - 1.0f) * 0.5f;
      float tx = ((cy + 1.0f) * 128.0f - 1.0f) * 0.5f;
      float fy = fminf(fmaxf(rintf(ty), 0.f), 127.f);   /* round half-even */
      float fx = fminf(fmaxf(rintf(tx), 0.f), 127.f);
      int iy = (int)fy, ix = (int)fx;
      float qcy = -1.0f + (2.0f * fy + 1.0f) * (1.0f / 128.0f);
      float qcx = -1.0f + (2.0f * fx + 1.0f) * (1.0f / 128.0f);
      float rel0 = (c0 - qcy) * 128.0f;
      float rel1 = (c1 - qcx) * 128.0f;
      float ar = fabsf(rel0 * rel1);
      tot += ar + 1e-9f;
      if (ci == 3) a3 = ar;
      const short* bp = Yb + ((size_t)(iy * 128 + ix)) * 512;
      float coefA = ldq(bp + j);          /* coef channel j    */
      float coefB = ldq(bp + 128 + j);    /* coef channel j+128 */
      float f0, f1;
      ldqpair(bp + 256 + 2 * j, f0, f1);  /* freq pair (2j,2j+1) */
      float f = f0 * rel0 + f1 * rel1 + ph;
      float ang = PIF * f;
      accC += coefA * __cosf(ang);
      accS += coefB * __sinf(ang);
    }
    const float wgt = a3 / tot;
    lout[j * 17 + qi]         = accC * wgt;
    lout[(j + 128) * 17 + qi] = accS * wgt;
  }
  __syncthreads();
#pragma unroll
  for (int pass = 0; pass < 8; ++pass) {
    int c  = pass * 32 + (j >> 2);
    int qf = (j & 3) * 4;
    float4 v;
    v.x = lout[c * 17 + qf];     v.y = lout[c * 17 + qf + 1];
    v.z = lout[c * 17 + qf + 2]; v.w = lout[c * 17 + qf + 3];
    *(float4*)(out + (((size_t)(b * 256 + c)) << 14) + q0loc + qf) = v;
  }
}

extern "C" void kernel_launch(void* const* d_in, const int* in_sizes, int n_in,
                              void* d_out, int out_size, void* d_ws, size_t ws_size,
                              hipStream_t stream) {
  const float* inp     = (const float*)d_in[0];
  const float* coord   = (const float*)d_in[1];
  const float* cell    = (const float*)d_in[2];
  const float* coef_w  = (const float*)d_in[3];
  const float* coef_b  = (const float*)d_in[4];
  const float* freq_w  = (const float*)d_in[5];
  const float* freq_b  = (const float*)d_in[6];
  const float* phase_w = (const float*)d_in[7];
  float* out = (float*)d_out;

  /* ws layout: Awp fp16 (0.59MB) | xp fp16 (8.39MB) | YT int16 (67.1MB). */
  f16* Awp = (f16*)d_ws;
  f16* xp  = (f16*)((char*)d_ws + (size_t)WELEM * 2);
  short* YT = (short*)((char*)d_ws + (size_t)WELEM * 2 + (size_t)NB * NPIX * 64 * 2);

  lte_prep_w<<<dim3(1152), dim3(256), 0, stream>>>(coef_w, freq_w, Awp);
  lte_prep_x<<<dim3(256),  dim3(256), 0, stream>>>(inp, xp);
  lte_conv_gemm<<<dim3(128, 4, 4), dim3(256), 0, stream>>>(xp, Awp, coef_b, freq_b, YT);
  lte_sample<<<dim3(4096), dim3(128), 0, stream>>>(YT, coord, cell, phase_w, out);
}

// Round 5
// 132.770 us; speedup vs baseline: 1.8410x; 1.0329x over previous
//
#include <hip/hip_runtime.h>

typedef unsigned short u16;
typedef _Float16 f16;

#define CIN   64
#define HH    128
#define WW    128
#define NPIX  16384   /* HH*WW */
#define HID   256
#define MTOT  512     /* coef(256) + freq(256) stacked */
#define KTOT  576     /* 64 ch * 9 taps */
#define NB    4
#define WELEM 294912  /* MTOT*KTOT */
#define XROW  130     /* padded input grid row */
#define XROWS 16900   /* 130*130 rows per batch */

/* index-path constants: must bit-match the f32 trace of the reference */
#define SHM  ((float)(-0.0078125 + 1e-6))
#define SHP  ((float)( 0.0078125 + 1e-6))
#define CLO  ((float)(-1.0 + 1e-6))
#define CHI  ((float)( 1.0 - 1e-6))
#define PIF  3.14159265358979323846f

#define QSCL  1024.0f          /* int16 fixed-point scale for YT */
#define QISCL (1.0f / 1024.0f)

using f32x4 = __attribute__((ext_vector_type(4))) float;
using f16x8 = __attribute__((ext_vector_type(8))) _Float16;

/* ---- async global->LDS DMA, 16B per lane (dest = wave base + lane*16) ---- */
typedef __attribute__((address_space(1))) const void gas_void;
typedef __attribute__((address_space(3))) void las_void;
__device__ __forceinline__ void gload16(const void* g, void* l) {
  __builtin_amdgcn_global_load_lds((gas_void*)g, (las_void*)l, 16, 0, 0);
}

/* ---- int16 fixed-point YT helpers ---- */
__device__ __forceinline__ float ldq(const short* p) { return (float)(*p) * QISCL; }
__device__ __forceinline__ void ldqpair(const short* p, float& a, float& b) {
  int u = *(const int*)p;
  a = (float)((short)(u & 0xFFFF)) * QISCL;
  b = (float)((short)(u >> 16)) * QISCL;
}
__device__ __forceinline__ unsigned packq(float a, float b) {
  float fa = fminf(fmaxf(a * QSCL, -32767.f), 32767.f);
  float fb = fminf(fmaxf(b * QSCL, -32767.f), 32767.f);
  int ia = (int)rintf(fa), ib = (int)rintf(fb);
  return ((unsigned)(unsigned short)(short)ia) | (((unsigned)(unsigned short)(short)ib) << 16);
}
__device__ __forceinline__ void storeq4(short* p, float a, float b, float c, float d) {
  uint2 v; v.x = packq(a, b); v.y = packq(c, d);
  *(uint2*)p = v;
}

/* =====================================================================
 * Kernel 1: repack conv weights -> fp16, pre-tiled per (m-tile, tap) AND
 * pre-XOR-swizzled for bank-conflict-free ds_read after linear DMA:
 * 16B chunk j of row i holds channels (j^(i&7))*8..+8 of tap s.
 * Awp[((mt*9+s)*128 + i)*64 + j*8 + e] = W[mt*128+i][(j^(i&7))*8+e][tap s]
 * ===================================================================== */
__global__ __launch_bounds__(256) void lte_prep_w(
    const float* __restrict__ cw, const float* __restrict__ fw,
    f16* __restrict__ Awp) {
  int id = blockIdx.x * 256 + threadIdx.x;
  if (id >= WELEM) return;
  int e  = id & 7;
  int j  = (id >> 3) & 7;
  int i  = (id >> 6) & 127;
  int t2 = id >> 13;            /* mt*9 + s */
  int mt = t2 / 9;
  int s  = t2 - mt * 9;
  int ch = ((j ^ (i & 7)) << 3) + e;
  int m  = mt * 128 + i;
  const float* src = (m < HID) ? cw : fw;
  Awp[id] = (f16)src[(m & 255) * KTOT + ch * 9 + s];
}

/* =====================================================================
 * Kernel 1b: input NCHW f32 -> zero-guard-padded pixel-major fp16
 * xp[b][130][130][64]; guard rows/cols are zeros so GEMM B-staging DMA
 * needs no boundary predication.
 * ===================================================================== */
__global__ __launch_bounds__(256) void lte_prep_x(
    const float* __restrict__ inp, f16* __restrict__ xp) {
  int id = blockIdx.x * 256 + threadIdx.x;   /* padded row id, NB*16900 */
  if (id >= NB * XROWS) return;
  int b  = id / XROWS;
  int rr = id - b * XROWS;
  int yy = rr / XROW;
  int x  = rr - yy * XROW - 1;
  int y  = yy - 1;
  f16* op = xp + (size_t)id * 64;
  if ((unsigned)y < 128u && (unsigned)x < 128u) {
    const float* ip = inp + (size_t)b * CIN * NPIX + y * WW + x;
#pragma unroll
    for (int q = 0; q < 8; ++q) {
      f16x8 v;
#pragma unroll
      for (int k = 0; k < 8; ++k) v[k] = (f16)ip[(q * 8 + k) * NPIX];
      *(f16x8*)(op + q * 8) = v;
    }
  } else {
    f16x8 z = {};
#pragma unroll
    for (int q = 0; q < 8; ++q) *(f16x8*)(op + q * 8) = z;
  }
}

/* =====================================================================
 * Kernel 2: implicit-im2col GEMM, Y = W(512x576) * patches(576x16384)
 * per batch, fp16 MFMA 16x16x32. 128x128 tile, 4 waves (2x2), 4x4 frags,
 * BK=64 (one tap x 64ch/step, 9 steps). m97 structure: global_load_lds
 * w=16 staging (zero staging VALU), linear 128B LDS rows, XOR-swizzled
 * sources + XOR on fragment reads (conflict-free b128).
 * Output pixel-major int16 YT[b][p][512] (+bias), scale 1024.
 * ===================================================================== */
__global__ __launch_bounds__(256) void lte_conv_gemm(
    const f16* __restrict__ xp, const f16* __restrict__ Awp,
    const float* __restrict__ coef_b, const float* __restrict__ freq_b,
    short* __restrict__ YT) {
  __shared__ f16 As[128 * 64];   /* 16 KB, [m-row][64 k], linear */
  __shared__ f16 Bs[128 * 64];   /* 16 KB, [pixel][64 ch], linear */

  const int t  = threadIdx.x;
  const int bx = blockIdx.x;     /* image row y; pixel tile = [bx*128,+128) */
  const int mt = blockIdx.y;     /* m tile (0..3) */
  const int bb = blockIdx.z;     /* batch */
  const int l  = t & 63;
  const int w  = t >> 6;
  const int wr = w >> 1, wc = w & 1;
  const int lm = l & 15;
  const int lm7 = lm & 7;
  const int kq = l >> 4;         /* fragment k-chunk 0..3 */
  const int lrow = l >> 3;       /* staging: pixel-in-call 0..7 */
  const int lchk = l & 7;        /* staging: 16B chunk 0..7 */
  const int w8 = w * 8;          /* wave's first staging call */

  f32x4 acc[4][4] = {};

  const f16* Atile = Awp + (size_t)(mt * 9) * 8192;
  const f16* xb = xp + (size_t)bb * XROWS * 64;

  /* stage step s_: 32 x 1KB DMA calls; calls 0..15 -> As, 16..31 -> Bs.
     A source is pre-swizzled linear; B source chunk = lchk ^ (px&7),
     px&7 == lrow. */
#define STAGE(s_)                                                            \
  {                                                                          \
    const int s__ = (s_);                                                    \
    const int ky = s__ / 3, kx = s__ - 3 * (s__ / 3);                        \
    const f16* asrc = Atile + s__ * 8192;                                    \
    const int grow0 = (bx + ky) * XROW + kx;                                 \
    _Pragma("unroll")                                                        \
    for (int i = 0; i < 8; ++i) {                                            \
      const int c = w8 + i;                                                  \
      if (c < 16) {                                                          \
        gload16(asrc + c * 512 + l * 8, As + c * 512);                       \
      } else {                                                               \
        const int cb = c - 16;                                               \
        const int px = cb * 8 + lrow;                                        \
        gload16(xb + (size_t)(grow0 + px) * 64 + ((lchk ^ lrow) << 3),       \
                Bs + cb * 512);                                              \
      }                                                                      \
    }                                                                        \
  }

  STAGE(0)
  __syncthreads();

  for (int s = 0; s < 9; ++s) {
#pragma unroll
    for (int ks = 0; ks < 2; ++ks) {
      const int jl = ks * 4 + kq;            /* logical 16B chunk 0..7 */
      const int pc = (jl ^ lm7) << 3;        /* physical half offset   */
      f16x8 af[4], bg[4];
#pragma unroll
      for (int mi = 0; mi < 4; ++mi)
        af[mi] = *(const f16x8*)&As[(wr * 64 + mi * 16 + lm) * 64 + pc];
#pragma unroll
      for (int ni = 0; ni < 4; ++ni)
        bg[ni] = *(const f16x8*)&Bs[(wc * 64 + ni * 16 + lm) * 64 + pc];
#pragma unroll
      for (int mi = 0; mi < 4; ++mi)
#pragma unroll
        for (int ni = 0; ni < 4; ++ni)
          acc[mi][ni] = __builtin_amdgcn_mfma_f32_16x16x32_f16(af[mi], bg[ni], acc[mi][ni], 0, 0, 0);
    }
    if (s < 8) {
      __syncthreads();          /* all frag reads done before overwrite */
      STAGE(s + 1)
      __syncthreads();          /* vmcnt(0) drain + staging visible */
    }
  }

  /* epilogue: +bias, quantize, store pixel-major YT[b][p][512] */
  const float* bias = (mt < 2) ? (coef_b + mt * 128) : (freq_b + (mt - 2) * 128);
  const int rj = (l >> 4) * 4;
#pragma unroll
  for (int mi = 0; mi < 4; ++mi) {
    const int bm = wr * 64 + mi * 16 + rj;
    const float b0 = bias[bm], b1 = bias[bm + 1], b2 = bias[bm + 2], b3 = bias[bm + 3];
#pragma unroll
    for (int ni = 0; ni < 4; ++ni) {
      const int p = bx * 128 + wc * 64 + ni * 16 + lm;
      size_t off = ((size_t)(bb * NPIX + p)) * 512 + mt * 128 + bm;
      f32x4 v = acc[mi][ni];
      storeq4(&YT[off], v[0] + b0, v[1] + b1, v[2] + b2, v[3] + b3);
    }
  }
}

/* =====================================================================
 * Kernel 3: 4-corner nearest sample + sin/cos modulation (int16 YT).
 * Validated bit-exact index path — unchanged.
 * ===================================================================== */
__global__ __launch_bounds__(128) void lte_sample(
    const short* __restrict__ YT, const float* __restrict__ coord,
    const float* __restrict__ cell, const float* __restrict__ phase_w,
    float* __restrict__ out) {
  __shared__ float lout[256 * 17];
  const int j     = threadIdx.x;          /* 0..127 */
  const int q0    = blockIdx.x * 16;      /* global over B*Q */
  const int b     = q0 >> 14;
  const int q0loc = q0 & (NPIX - 1);
  const float pw0 = phase_w[2 * j], pw1 = phase_w[2 * j + 1];
  const short* Yb = YT + ((size_t)b * NPIX) * 512;

  for (int qi = 0; qi < 16; ++qi) {
    const int qg = q0 + qi;
    const float c0  = coord[2 * qg], c1 = coord[2 * qg + 1];
    const float ce0 = cell[2 * qg],  ce1 = cell[2 * qg + 1];
    const float ph  = (ce0 * 128.0f) * pw0 + (ce1 * 128.0f) * pw1;
    float accC = 0.f, accS = 0.f, tot = 0.f, a3 = 0.f;
#pragma unroll
    for (int ci = 0; ci < 4; ++ci) {     /* (vx,vy): (-,-),(-,+),(+,-),(+,+) */
      const float s0 = (ci & 2) ? SHP : SHM;
      const float s1 = (ci & 1) ? SHP : SHM;
      float cx = fminf(fmaxf(c0 + s0, CLO), CHI);
      float cy = fminf(fmaxf(c1 + s1, CLO), CHI);
      float ty = ((cx + 1.0f) * 128.0f - 1.0f) * 0.5f;
      float tx = ((cy + 1.0f) * 128.0f - 1.0f) * 0.5f;
      float fy = fminf(fmaxf(rintf(ty), 0.f), 127.f);   /* round half-even */
      float fx = fminf(fmaxf(rintf(tx), 0.f), 127.f);
      int iy = (int)fy, ix = (int)fx;
      float qcy = -1.0f + (2.0f * fy + 1.0f) * (1.0f / 128.0f);
      float qcx = -1.0f + (2.0f * fx + 1.0f) * (1.0f / 128.0f);
      float rel0 = (c0 - qcy) * 128.0f;
      float rel1 = (c1 - qcx) * 128.0f;
      float ar = fabsf(rel0 * rel1);
      tot += ar + 1e-9f;
      if (ci == 3) a3 = ar;
      const short* bp = Yb + ((size_t)(iy * 128 + ix)) * 512;
      float coefA = ldq(bp + j);          /* coef channel j    */
      float coefB = ldq(bp + 128 + j);    /* coef channel j+128 */
      float f0, f1;
      ldqpair(bp + 256 + 2 * j, f0, f1);  /* freq pair (2j,2j+1) */
      float f = f0 * rel0 + f1 * rel1 + ph;
      float ang = PIF * f;
      accC += coefA * __cosf(ang);
      accS += coefB * __sinf(ang);
    }
    const float wgt = a3 / tot;
    lout[j * 17 + qi]         = accC * wgt;
    lout[(j + 128) * 17 + qi] = accS * wgt;
  }
  __syncthreads();
#pragma unroll
  for (int pass = 0; pass < 8; ++pass) {
    int c  = pass * 32 + (j >> 2);
    int qf = (j & 3) * 4;
    float4 v;
    v.x = lout[c * 17 + qf];     v.y = lout[c * 17 + qf + 1];
    v.z = lout[c * 17 + qf + 2]; v.w = lout[c * 17 + qf + 3];
    *(float4*)(out + (((size_t)(b * 256 + c)) << 14) + q0loc + qf) = v;
  }
}

extern "C" void kernel_launch(void* const* d_in, const int* in_sizes, int n_in,
                              void* d_out, int out_size, void* d_ws, size_t ws_size,
                              hipStream_t stream) {
  const float* inp     = (const float*)d_in[0];
  const float* coord   = (const float*)d_in[1];
  const float* cell    = (const float*)d_in[2];
  const float* coef_w  = (const float*)d_in[3];
  const float* coef_b  = (const float*)d_in[4];
  const float* freq_w  = (const float*)d_in[5];
  const float* freq_b  = (const float*)d_in[6];
  const float* phase_w = (const float*)d_in[7];
  float* out = (float*)d_out;

  /* ws layout: Awp fp16 (0.59MB) | xp_pad fp16 (8.65MB) | YT int16 (67.1MB). */
  f16* Awp = (f16*)d_ws;
  f16* xp  = (f16*)((char*)d_ws + (size_t)WELEM * 2);
  short* YT = (short*)((char*)d_ws + (size_t)WELEM * 2 + (size_t)NB * XROWS * 64 * 2);

  lte_prep_w<<<dim3(1152), dim3(256), 0, stream>>>(coef_w, freq_w, Awp);
  lte_prep_x<<<dim3((NB * XROWS + 255) / 256), dim3(256), 0, stream>>>(inp, xp);
  lte_conv_gemm<<<dim3(128, 4, 4), dim3(256), 0, stream>>>(xp, Awp, coef_b, freq_b, YT);
  lte_sample<<<dim3(4096), dim3(128), 0, stream>>>(YT, coord, cell, phase_w, out);
}